// Round 6
// baseline (259.926 us; speedup 1.0000x reference)
//
#include <hip/hip_runtime.h>
#include <stdint.h>

#define HID   2048
#define NE    64
#define BATCH 4
#define SEQ   4096
#define CAP   128
#define TM    32                  // tokens per block
#define NKS   (HID / 32)          // 64 k-steps of 32

typedef __attribute__((ext_vector_type(8))) short s16x8;   // 8 bf16 = 4 VGPR
typedef __attribute__((ext_vector_type(4))) float f32x4;

union V16 { uint4 u; s16x8 s; };

// Exact 3-term bf16 bit-slice: v = h0 + h1 + h2 exactly (8+8+8 >= 24 mantissa
// bits, truncation slicing). Validated numerically in round 3 (passed).
__device__ __forceinline__ void split1(float v, unsigned& b0, unsigned& b1, unsigned& b2) {
    unsigned b = __float_as_uint(v);
    b0 = b & 0xffff0000u;
    float r1 = v - __uint_as_float(b0);
    unsigned c = __float_as_uint(r1);
    b1 = c & 0xffff0000u;
    float r2 = r1 - __uint_as_float(b1);
    b2 = __float_as_uint(r2) & 0xffff0000u;
}

// fp32 pair (even k, odd k) -> one dword per plane; low16 = even k.
// Identical packing to round-3's validated pack8.
__device__ __forceinline__ void splitpair(float e, float o, unsigned& d0, unsigned& d1, unsigned& d2) {
    unsigned a0, a1, a2, c0, c1, c2;
    split1(e, a0, a1, a2);
    split1(o, c0, c1, c2);
    d0 = (a0 >> 16) | c0;
    d1 = (a1 >> 16) | c1;
    d2 = (a2 >> 16) | c2;
}

// ---------------------------------------------------------------------------
// Pre-kernel: convert W (64 x 2048 fp32) into MFMA-B-fragment-canonical bf16x3
// planes. Fragment (ksg, bt, p): 64 lanes x 16B; lane l holds
// plane_p(W)[ expert = bt*16 + (l&15) ][ k = ksg*32 + (l>>4)*8 .. +8 ]
// (ascending k, low16 = even k) — exactly the layout round 3's validated LDS
// B-read delivered. Wf index: ((ksg*4 + bt)*3 + p)*64 + lane.
// ---------------------------------------------------------------------------
__global__ __launch_bounds__(256) void wconv_kernel(
    const float* __restrict__ W, uint4* __restrict__ Wf)
{
    const int g    = blockIdx.x * 256 + threadIdx.x;   // 16384 threads
    const int lane = g & 63;
    const int bt   = (g >> 6) & 3;
    const int ksg  = g >> 8;                           // 0..63
    const int e    = bt * 16 + (lane & 15);
    const int k0   = ksg * 32 + (lane >> 4) * 8;

    const float4 fa = *(const float4*)(W + (size_t)e * HID + k0);
    const float4 fb = *(const float4*)(W + (size_t)e * HID + k0 + 4);

    unsigned q0[4], q1[4], q2[4];
    splitpair(fa.x, fa.y, q0[0], q1[0], q2[0]);
    splitpair(fa.z, fa.w, q0[1], q1[1], q2[1]);
    splitpair(fb.x, fb.y, q0[2], q1[2], q2[2]);
    splitpair(fb.z, fb.w, q0[3], q1[3], q2[3]);

    const int fb3 = (ksg * 4 + bt) * 3;
    Wf[(size_t)(fb3 + 0) * 64 + lane] = make_uint4(q0[0], q0[1], q0[2], q0[3]);
    Wf[(size_t)(fb3 + 1) * 64 + lane] = make_uint4(q1[0], q1[1], q1[2], q1[3]);
    Wf[(size_t)(fb3 + 2) * 64 + lane] = make_uint4(q2[0], q2[1], q2[2], q2[3]);
}

// ---------------------------------------------------------------------------
// Router: barrier-free streaming GEMM. 512 blocks x 256 threads (4 waves,
// wave grid 2 token-tiles x 2 bt-pairs). x -> A-fragments directly from
// global (per-lane 32B), split in-register; W fragments from Wf (coalesced
// 1KB wave reads, L2-resident). 6-pass bf16x3 MFMA (00,01,10,02,11,20).
// LDS only for the 8.5 KB epilogue logits bounce. No barriers in the K-loop.
// ---------------------------------------------------------------------------
__global__ __launch_bounds__(256, 2) void router_mfma_kernel(
    const float* __restrict__ x,       // (B*S, HID)
    const uint4* __restrict__ Wf,      // canonical W fragments
    const float* __restrict__ bias,    // (NE)
    float* __restrict__ out_ind,       // (B*S, NE) zeroed here
    float* __restrict__ out_probs,     // (B*S)
    float* __restrict__ logits_out,    // (B*S, NE)
    int* __restrict__ eidx)            // (B*S) ws: argmax expert
{
    __shared__ float lg[TM][68];       // 8.5 KB, +4 pad (2-way max on stores, free)

    const int tid  = threadIdx.x;
    const int m0   = blockIdx.x * TM;
    const int w    = tid >> 6;
    const int wr   = w >> 1;           // token tile (16 rows)
    const int wc   = w & 1;            // bt pair: experts 32*wc .. +31
    const int lane = tid & 63;
    const int l15  = lane & 15;
    const int l4   = lane >> 4;

    // A source: lane l reads x[token = m0+16*wr+(l&15)][(l>>4)*8 + 32*ks .. +8]
    const float* xp = x + (size_t)(m0 + 16 * wr + l15) * HID + l4 * 8;
    // B fragments: base at (ksg=0, bt=2*wc, p=0)
    const uint4* wp = Wf + (size_t)(wc * 2) * 3 * 64 + lane;

    f32x4 acc[2];
    acc[0] = (f32x4){0.f, 0.f, 0.f, 0.f};
    acc[1] = (f32x4){0.f, 0.f, 0.f, 0.f};

#pragma unroll 2
    for (int ks = 0; ks < NKS; ++ks) {
        const float4 xa = *(const float4*)(xp + ks * 32);
        const float4 xb = *(const float4*)(xp + ks * 32 + 4);
        const uint4* wk = wp + (size_t)ks * 12 * 64;   // ksg stride = 4bt x 3p frags
        V16 B00, B01, B02, B10, B11, B12;
        B00.u = wk[0 * 64]; B01.u = wk[1 * 64]; B02.u = wk[2 * 64];
        B10.u = wk[3 * 64]; B11.u = wk[4 * 64]; B12.u = wk[5 * 64];

        unsigned q0[4], q1[4], q2[4];
        splitpair(xa.x, xa.y, q0[0], q1[0], q2[0]);
        splitpair(xa.z, xa.w, q0[1], q1[1], q2[1]);
        splitpair(xb.x, xb.y, q0[2], q1[2], q2[2]);
        splitpair(xb.z, xb.w, q0[3], q1[3], q2[3]);
        V16 A0, A1, A2;
        A0.u = make_uint4(q0[0], q0[1], q0[2], q0[3]);
        A1.u = make_uint4(q1[0], q1[1], q1[2], q1[3]);
        A2.u = make_uint4(q2[0], q2[1], q2[2], q2[3]);

        // 6-pass exact fp32-via-bf16 (same pass set round 3 validated)
        acc[0] = __builtin_amdgcn_mfma_f32_16x16x32_bf16(A0.s, B00.s, acc[0], 0, 0, 0);
        acc[0] = __builtin_amdgcn_mfma_f32_16x16x32_bf16(A0.s, B01.s, acc[0], 0, 0, 0);
        acc[0] = __builtin_amdgcn_mfma_f32_16x16x32_bf16(A1.s, B00.s, acc[0], 0, 0, 0);
        acc[0] = __builtin_amdgcn_mfma_f32_16x16x32_bf16(A0.s, B02.s, acc[0], 0, 0, 0);
        acc[0] = __builtin_amdgcn_mfma_f32_16x16x32_bf16(A1.s, B01.s, acc[0], 0, 0, 0);
        acc[0] = __builtin_amdgcn_mfma_f32_16x16x32_bf16(A2.s, B00.s, acc[0], 0, 0, 0);

        acc[1] = __builtin_amdgcn_mfma_f32_16x16x32_bf16(A0.s, B10.s, acc[1], 0, 0, 0);
        acc[1] = __builtin_amdgcn_mfma_f32_16x16x32_bf16(A0.s, B11.s, acc[1], 0, 0, 0);
        acc[1] = __builtin_amdgcn_mfma_f32_16x16x32_bf16(A1.s, B10.s, acc[1], 0, 0, 0);
        acc[1] = __builtin_amdgcn_mfma_f32_16x16x32_bf16(A0.s, B12.s, acc[1], 0, 0, 0);
        acc[1] = __builtin_amdgcn_mfma_f32_16x16x32_bf16(A1.s, B11.s, acc[1], 0, 0, 0);
        acc[1] = __builtin_amdgcn_mfma_f32_16x16x32_bf16(A2.s, B10.s, acc[1], 0, 0, 0);
    }

    // ---- epilogue: C/D layout (m89-verified): col = lane&15, row = l4*4+reg --
    const int tb = 16 * wr + 4 * l4;
#pragma unroll
    for (int btl = 0; btl < 2; ++btl) {
        const int e = 32 * wc + 16 * btl + l15;
        const float bb = bias[e];
#pragma unroll
        for (int rr = 0; rr < 4; ++rr)
            lg[tb + rr][e] = acc[btl][rr] + bb;
    }
    __syncthreads();

    // stats: 8 threads per token, 8 experts each
    {
        const int tok = tid >> 3, part = tid & 7;
        float vals[8];
        const float4 v0 = *(const float4*)&lg[tok][part * 8];
        const float4 v1 = *(const float4*)&lg[tok][part * 8 + 4];
        vals[0] = v0.x; vals[1] = v0.y; vals[2] = v0.z; vals[3] = v0.w;
        vals[4] = v1.x; vals[5] = v1.y; vals[6] = v1.z; vals[7] = v1.w;
        float m = vals[0];
        int  mi = part * 8;
#pragma unroll
        for (int j = 1; j < 8; ++j)
            if (vals[j] > m) { m = vals[j]; mi = part * 8 + j; }
#pragma unroll
        for (int mm = 1; mm <= 4; mm <<= 1) {
            const float om = __shfl_xor(m, mm);
            const int   oi = __shfl_xor(mi, mm);
            if (om > m || (om == m && oi < mi)) { m = om; mi = oi; }
        }
        float s = 0.f;
#pragma unroll
        for (int j = 0; j < 8; ++j) s += __expf(vals[j] - m);
#pragma unroll
        for (int mm = 1; mm <= 4; mm <<= 1) s += __shfl_xor(s, mm);
        if (part == 0) {
            out_probs[m0 + tok] = 1.f / s;   // max prob = 1/sum(exp(l-max))
            eidx[m0 + tok] = mi;
        }
    }

    // coalesced logits store + zero expert_indices slice
    {
        float4* lout = (float4*)(logits_out + (size_t)m0 * NE);
        float4* oz   = (float4*)(out_ind + (size_t)m0 * NE);
        const float4 z4 = make_float4(0.f, 0.f, 0.f, 0.f);
#pragma unroll
        for (int i = 0; i < 2; ++i) {
            const int fi = tid + 256 * i;            // 512 float4 total
            const int row = fi >> 4, c4 = fi & 15;
            lout[fi] = *(const float4*)&lg[row][c4 * 4];
            oz[fi] = z4;
        }
    }
}

// ---------------------------------------------------------------------------
// Capacity scan (validated rounds 1&3): 1 wave per (batch, expert), ballot +
// prefix popcount inclusive cumsum over the sequence; 1.0 where rank <= CAP.
// ---------------------------------------------------------------------------
__device__ __forceinline__ void cap_step(int v, int e, int lane, int s_abs,
                                         float* col, int& run) {
    const unsigned long long mm = __ballot(v == e);
    if (v == e) {
        const int rank = run + __popcll(mm & ((1ull << lane) - 1ull)) + 1;
        if (rank <= CAP) col[(size_t)(s_abs + lane) * NE] = 1.0f;
    }
    run += __popcll(mm);
}

__global__ __launch_bounds__(64) void capacity_kernel(
    const int* __restrict__ eidx, float* __restrict__ out_ind)
{
    const int lane = threadIdx.x;
    const int b = blockIdx.x >> 6;
    const int e = blockIdx.x & 63;
    const int* row = eidx + (size_t)b * SEQ;
    float* col = out_ind + (size_t)b * SEQ * NE + e;
    int run = 0;
    for (int s0 = 0; s0 < SEQ; s0 += 256) {
        const int v0 = row[s0 + lane];
        const int v1 = row[s0 + 64 + lane];
        const int v2 = row[s0 + 128 + lane];
        const int v3 = row[s0 + 192 + lane];
        cap_step(v0, e, lane, s0, col, run);
        cap_step(v1, e, lane, s0 + 64, col, run);
        cap_step(v2, e, lane, s0 + 128, col, run);
        cap_step(v3, e, lane, s0 + 192, col, run);
    }
}

// ---------------------------------------------------------------------------
extern "C" void kernel_launch(void* const* d_in, const int* in_sizes, int n_in,
                              void* d_out, int out_size, void* d_ws, size_t ws_size,
                              hipStream_t stream)
{
    const float* x    = (const float*)d_in[0];
    const float* W    = (const float*)d_in[1];
    const float* bias = (const float*)d_in[2];

    float* out_ind   = (float*)d_out;
    float* out_probs = out_ind + (size_t)BATCH * SEQ * NE;
    float* logits    = out_probs + (size_t)BATCH * SEQ;

    int*   eidx = (int*)d_ws;                                   // 64 KiB
    uint4* Wf   = (uint4*)((char*)d_ws + 65536);                // 768 KiB

    wconv_kernel<<<64, 256, 0, stream>>>(W, Wf);
    router_mfma_kernel<<<(BATCH * SEQ) / TM, 256, 0, stream>>>(
        x, Wf, bias, out_ind, out_probs, logits, eidx);
    capacity_kernel<<<BATCH * NE, 64, 0, stream>>>(eidx, out_ind);
}